// Round 5
// baseline (231.851 us; speedup 1.0000x reference)
//
#include <hip/hip_runtime.h>

// DWT db4 depthwise stride-2 decomposition.
// x: [B=32, T=16384, C=64] f32 -> out: [B, T2=8190, 2C=128] f32
// out[b,t,c]    = sum_k lo[k] * x[b, reflect(2t+k-1), c]      (c < 64)
// out[b,t,64+c] = sum_k hi[k] * x[b, reflect(2t+k-1), c]
// reflect: m<0 -> -m ; m>T-1 -> 2(T-1)-m
//
// R5: LDS-tiled. Register-window variants (R1/R2/R4) all hit a flat
// ~2.6 TB/s wall: compiler serializes loads (VGPR=36, vmcnt chunks) and the
// scattered 1.875x over-read burns L1 miss-queue depth. Here each block
// stages 136 contiguous rows (34.8 KB) into LDS via async global_load_lds --
// every cache line fetched exactly once, fill-like sequential bursts, 9
// outstanding 1KB wave-loads with no vmcnt wait until the barrier. Compute
// reads LDS (conflict-free: 16 lanes x 16B = 256B contiguous = 2-way, free),
// nt-stores the write-once output.

#define BT    32
#define TT    16384
#define CC    64
#define T2    8190        // T/2 - 2
#define OC    128         // 2*CC
#define TB    64          // outputs (t) per tile
#define NTILE ((T2 + TB - 1) / TB)   // 128
#define SLOTS 2304        // 9 iters * 256 threads, float4 slots (144 rows; need 135)

typedef float vf4 __attribute__((ext_vector_type(4)));

__global__ __launch_bounds__(256, 4) void dwt_db4_lds_kernel(
    const float* __restrict__ x,
    const float* __restrict__ dec_lo,
    const float* __restrict__ dec_hi,
    float* __restrict__ out)
{
    __shared__ float lds[SLOTS * 4];        // 36864 B -> 4 blocks/CU

    const int tid  = threadIdx.x;
    const int tile = blockIdx.x;
    const int b    = blockIdx.y;

    const int t0 = tile * TB;
    const int m0 = 2 * t0 - 1;              // first staged input row

    const float* __restrict__ xb = x + (size_t)b * TT * CC;

    // Filters: uniform scalar broadcast loads.
    float flo[8], fhi[8];
    #pragma unroll
    for (int k = 0; k < 8; ++k) { flo[k] = dec_lo[k]; fhi[k] = dec_hi[k]; }

    // ---- async stage: rows m0 .. m0+143 (reflect-mapped), 16B/lane ----
    const int lane = tid & 63;
    const int wv   = tid >> 6;              // wave 0..3
    #pragma unroll
    for (int it = 0; it < 9; ++it) {
        const int base = it * 256 + wv * 64;        // wave-uniform slot base
        const int slot = base + lane;
        const int r    = slot >> 4;                 // staged row 0..143
        const int c4   = (slot & 15) * 4;           // float column 0..60
        int m  = m0 + r;
        int mm = m < 0 ? -m : m;                          // left reflect
        mm     = mm > (TT - 1) ? 2 * (TT - 1) - mm : mm;  // right reflect
        const float* gp = xb + (size_t)mm * CC + c4;
        __builtin_amdgcn_global_load_lds(
            (const __attribute__((address_space(1))) unsigned int*)gp,
            (__attribute__((address_space(3))) unsigned int*)&lds[(size_t)base * 4],
            16, 0, 0);
    }
    __syncthreads();

    // ---- compute: thread = (4 channels, 4 consecutive t) ----
    const int cg = tid & 15;                // channel group
    const int ts = tid >> 4;                // t-slot 0..15
    const int c4 = cg * 4;

    // local rows needed: lr = 8*ts + (0..13)
    vf4 w[14];
    #pragma unroll
    for (int i = 0; i < 14; ++i)
        w[i] = *reinterpret_cast<const vf4*>(&lds[(size_t)(8 * ts + i) * CC + c4]);

    vf4 alo[4], ahi[4];
    #pragma unroll
    for (int j = 0; j < 4; ++j) { alo[j] = (vf4)0.0f; ahi[j] = (vf4)0.0f; }

    #pragma unroll
    for (int j = 0; j < 4; ++j) {
        #pragma unroll
        for (int k = 0; k < 8; ++k) {
            const vf4 v = w[2 * j + k];
            alo[j] += flo[k] * v;
            ahi[j] += fhi[k] * v;
        }
    }

    const int tbase = t0 + ts * 4;
    float* __restrict__ ob = out + (size_t)b * T2 * OC + (size_t)tbase * OC;
    #pragma unroll
    for (int j = 0; j < 4; ++j) {
        if (tbase + j < T2) {
            __builtin_nontemporal_store(alo[j],
                reinterpret_cast<vf4*>(ob + (size_t)j * OC + c4));
            __builtin_nontemporal_store(ahi[j],
                reinterpret_cast<vf4*>(ob + (size_t)j * OC + CC + c4));
        }
    }
}

extern "C" void kernel_launch(void* const* d_in, const int* in_sizes, int n_in,
                              void* d_out, int out_size, void* d_ws, size_t ws_size,
                              hipStream_t stream)
{
    const float* x      = (const float*)d_in[0];
    const float* dec_lo = (const float*)d_in[1];
    const float* dec_hi = (const float*)d_in[2];
    float*       out    = (float*)d_out;

    dim3 block(256);
    dim3 grid(NTILE, BT);   // 128 x 32 = 4096 blocks

    hipLaunchKernelGGL(dwt_db4_lds_kernel, grid, block, 0, stream,
                       x, dec_lo, dec_hi, out);
}